// Round 4
// baseline (273.739 us; speedup 1.0000x reference)
//
#include <hip/hip_runtime.h>

#define NN 4096

typedef __attribute__((ext_vector_type(8))) short short8;
typedef __attribute__((ext_vector_type(4))) float f32x4;

// fp32 -> bf16 round-to-nearest-even
static __device__ __forceinline__ unsigned short f2bf(float x) {
    unsigned int u = __float_as_uint(x);
    u += 0x7fffu + ((u >> 16) & 1u);
    return (unsigned short)(u >> 16);
}

// async global->LDS, 16 bytes per lane (dest = wave-uniform base + lane*16)
static __device__ __forceinline__ void load_lds16(const unsigned short* g, unsigned short* l) {
    __builtin_amdgcn_global_load_lds(
        (const __attribute__((address_space(1))) unsigned int*)g,
        (__attribute__((address_space(3))) unsigned int*)l,
        16, 0, 0);
}

// XOR-swizzled byte offset inside one 16KB K-subtile (256 rows x 32 k bf16, row = 64B).
// phys = logical ^ (((logical>>7)&7)<<4): involution on 16B chunks within 128B pairs.
// ds_read_b128 column reads (16 rows, stride 64B) spread across 8 16B slots -> conflict-free
// (verified round 3: SQ_LDS_BANK_CONFLICT = 0).
static __device__ __forceinline__ int swz_byte(int row, int byte_in_row) {
    return (row * 64 + byte_in_row) ^ (((row >> 1) & 7) << 4);
}

// ---------------- fused pre-pass: pack A & B into tiled+swizzled bf16 ----------------
// A2 layout: [bi(16)][kb32(128)][16KB tile of 256 rows x 32 k], only kb32 < (bi+1)*8 written.
// B2 layout: [bjn(16)][kb32(128)][16KB tile of 256 n-rows x 32 k] (B^T), kb32 >= bjn*8.
// blocks [0,1088): B pack (heavy, dispatch first); [1088,2176): A pack.
// C zeroing is done by hipMemsetAsync in the launcher.
__global__ __launch_bounds__(256) void prep_all(const float* __restrict__ A,
                                                const float* __restrict__ B,
                                                unsigned short* __restrict__ A2,
                                                unsigned short* __restrict__ B2) {
    __shared__ unsigned short tbf[32][264];   // 16.5 KB -> 8 blocks/CU
    const int b   = blockIdx.x;
    const int tid = threadIdx.x;

    if (b < 1088) {
        // ---- pack B tile (bjn, kb32): n rows bjn*256..+255, k = kb32*32..+31, mask k>=n ----
        int rem = b, bjn;
        for (bjn = 0; bjn < 16; ++bjn) { int cnt = 128 - bjn * 8; if (rem < cnt) break; rem -= cnt; }
        const int kb = bjn * 8 + rem;
        // stage 32(k) x 256(n) block of B, coalesced f32 reads, convert to bf16 on the fly
        #pragma unroll
        for (int p = 0; p < 8; ++p) {
            int id   = p * 256 + tid;
            int krow = id >> 6;              // 0..31
            int c4   = (id & 63) << 2;       // 0..252
            const float4 v = *(const float4*)(B + (size_t)(kb * 32 + krow) * NN + bjn * 256 + c4);
            tbf[krow][c4 + 0] = f2bf(v.x); tbf[krow][c4 + 1] = f2bf(v.y);
            tbf[krow][c4 + 2] = f2bf(v.z); tbf[krow][c4 + 3] = f2bf(v.w);
        }
        __syncthreads();
        unsigned short* out = B2 + (size_t)bjn * 1048576 + (size_t)kb * 8192;
        const int n  = tid;                  // 0..255
        const int ng = bjn * 256 + n;
        #pragma unroll
        for (int kc = 0; kc < 4; ++kc) {
            short8 o;
            #pragma unroll
            for (int e = 0; e < 8; ++e) {
                int kg = kb * 32 + kc * 8 + e;
                o[e] = (kg >= ng) ? (short)tbf[kc * 8 + e][n] : (short)0;
            }
            *(short8*)&out[swz_byte(n, kc * 16) >> 1] = o;
        }
    } else {
        // ---- pack A tile (bi, kb32): rows bi*256..+255, k = kb32*32..+31, mask k<=i ----
        int rem = b - 1088, bi;
        for (bi = 0; bi < 16; ++bi) { int cnt = (bi + 1) * 8; if (rem < cnt) break; rem -= cnt; }
        const int kb = rem;
        unsigned short* out = A2 + (size_t)bi * 1048576 + (size_t)kb * 8192;
        #pragma unroll
        for (int p = 0; p < 8; ++p) {
            int id  = p * 256 + tid;
            int row = id >> 3;               // 0..255
            int c4  = (id & 7) << 2;         // 0..28 (k within tile)
            const int gi = bi * 256 + row;
            const int kg = kb * 32 + c4;
            const float4 v = *(const float4*)(A + (size_t)gi * NN + kg);
            ushort4 o;
            o.x = (kg + 0 <= gi) ? f2bf(v.x) : (unsigned short)0;
            o.y = (kg + 1 <= gi) ? f2bf(v.y) : (unsigned short)0;
            o.z = (kg + 2 <= gi) ? f2bf(v.z) : (unsigned short)0;
            o.w = (kg + 3 <= gi) ? f2bf(v.w) : (unsigned short)0;
            *(ushort4*)&out[swz_byte(row, c4 * 2) >> 1] = o;
        }
    }
}

// ---------------- main GEMM: 256x256 tile, BK=64, dbuf + counted-vmcnt pipeline ----------------
// 260 units: tile (bi,bj), D=bi-bj, m=ceil((D+1)/4) balanced split-K chunks, deepest-D first,
// XCD-chunked bijective block map. 8 waves (2x4), LDS 128KB (2 bufs x (32KB A + 32KB B)).
// Pipeline (T3+T4): 2-deep prefetch via global_load_lds; s_waitcnt vmcnt(8) keeps the next
// tile's loads in flight across the barrier (never drains to 0 mid-loop).
__global__ __launch_bounds__(512, 2) void gemm_tril(const unsigned short* __restrict__ A2,
                                                    const unsigned short* __restrict__ B2,
                                                    float* __restrict__ C) {
    const int tid = threadIdx.x;

    // bijective XCD-chunked map: one XCD gets a contiguous run of units
    const int bidx = (int)blockIdx.x;
    const int xcd = bidx & 7, ix = bidx >> 3;
    int u = (xcd < 4 ? xcd * 33 : 132 + (xcd - 4) * 32) + ix;

    // decode unit (sorted deepest-D first) -> (D, tile, chunk)
    int D, m = 1, rem = u;
    for (D = 15; D >= 0; --D) {
        m = (D + 4) >> 2;                    // ceil((D+1)/4)
        int cnt = (16 - D) * m;
        if (rem < cnt) break;
        rem -= cnt;
    }
    const int blk = rem / m;
    const int c   = rem - blk * m;
    const int bj = blk, bi = blk + D;
    const int S64 = (D + 1) * 4;             // K-steps (of 64) for the whole tile
    const int kt0 = bj * 4 + (c * S64) / m;
    const int kt1 = bj * 4 + ((c + 1) * S64) / m;
    const int nt  = kt1 - kt0;

    __shared__ __attribute__((aligned(16))) unsigned short As[2][16384];
    __shared__ __attribute__((aligned(16))) unsigned short Bs[2][16384];

    const int lane = tid & 63;
    const int w    = tid >> 6;               // 0..7
    const int wm   = w >> 2, wn = w & 3;     // 2 x 4 wave grid: 128 x 64 per wave
    const int l15  = lane & 15, quad = lane >> 4;

    f32x4 acc[8][4];
    const f32x4 zero4 = {0.f, 0.f, 0.f, 0.f};
    #pragma unroll
    for (int i = 0; i < 8; ++i)
        #pragma unroll
        for (int j = 0; j < 4; ++j) acc[i][j] = zero4;

    // one BK=64 step = two consecutive packed 16KB subtiles = 32KB contiguous per matrix
    const unsigned short* Atile = A2 + (size_t)bi * 1048576 + tid * 8;
    const unsigned short* Btile = B2 + (size_t)bj * 1048576 + tid * 8;

    auto STAGE = [&](int buf, int kt) {       // 8 x 16B loads/thread, in flight = +8 vmcnt
        const unsigned short* ga = Atile + (size_t)kt * 16384;
        const unsigned short* gb = Btile + (size_t)kt * 16384;
        #pragma unroll
        for (int r = 0; r < 4; ++r) {
            load_lds16(ga + r * 4096, &As[buf][tid * 8 + r * 4096]);
            load_lds16(gb + r * 4096, &Bs[buf][tid * 8 + r * 4096]);
        }
    };

    auto COMPUTE = [&](int buf) {
        #pragma unroll
        for (int h = 0; h < 2; ++h) {        // two 16KB k-halves of the BK=64 step
            short8 a[8], bq[4];
            #pragma unroll
            for (int mt = 0; mt < 8; ++mt) {
                int r = wm * 128 + mt * 16 + l15;
                a[mt] = *(const short8*)&As[buf][h * 8192 + (swz_byte(r, quad * 16) >> 1)];
            }
            #pragma unroll
            for (int nt2 = 0; nt2 < 4; ++nt2) {
                int r = wn * 64 + nt2 * 16 + l15;
                bq[nt2] = *(const short8*)&Bs[buf][h * 8192 + (swz_byte(r, quad * 16) >> 1)];
            }
            #pragma unroll
            for (int mt = 0; mt < 8; ++mt)
                #pragma unroll
                for (int nt2 = 0; nt2 < 4; ++nt2)
                    acc[mt][nt2] = __builtin_amdgcn_mfma_f32_16x16x32_bf16(a[mt], bq[nt2], acc[mt][nt2], 0, 0, 0);
        }
    };

    // prologue: 2-deep prefetch
    STAGE(0, kt0);
    if (nt > 1) STAGE(1, kt0 + 1);

    for (int i = 0; i < nt; ++i) {
        // wait for tile i's 8 loads only; tile i+1's stay in flight (counted vmcnt, T4)
        if (i + 1 < nt) asm volatile("s_waitcnt vmcnt(8)" ::: "memory");
        else            asm volatile("s_waitcnt vmcnt(0)" ::: "memory");
        __builtin_amdgcn_s_barrier();            // all waves' tile-i loads landed
        __builtin_amdgcn_sched_barrier(0);       // ds_reads must not hoist above barrier
        COMPUTE(i & 1);
        if (i + 2 < nt) {
            // all my ds_reads of buf (i&1) complete before anyone overwrites it
            asm volatile("s_waitcnt lgkmcnt(0)" ::: "memory");
            __builtin_amdgcn_s_barrier();
            __builtin_amdgcn_sched_barrier(0);
            STAGE(i & 1, kt0 + i + 2);
        }
    }

    // epilogue: C/D layout col=lane&15, row=quad*4+reg (m89-verified)
    if (m == 1) {
        // D<=3: sole owner, direct store (diagonal mask only when D==0)
        #pragma unroll
        for (int mt = 0; mt < 8; ++mt) {
            #pragma unroll
            for (int nt2 = 0; nt2 < 4; ++nt2) {
                const int gj  = bj * 256 + wn * 64 + nt2 * 16 + l15;
                const int gi0 = bi * 256 + wm * 128 + mt * 16 + quad * 4;
                #pragma unroll
                for (int rr = 0; rr < 4; ++rr) {
                    int gi = gi0 + rr;
                    float v = acc[mt][nt2][rr];
                    C[(size_t)gi * NN + gj] = (D > 0 || gi >= gj) ? v : 0.f;
                }
            }
        }
    } else {
        // partial contribution: C pre-zeroed by memset; D>=4 so strictly lower, no mask
        #pragma unroll
        for (int mt = 0; mt < 8; ++mt) {
            #pragma unroll
            for (int nt2 = 0; nt2 < 4; ++nt2) {
                const int gj  = bj * 256 + wn * 64 + nt2 * 16 + l15;
                const int gi0 = bi * 256 + wm * 128 + mt * 16 + quad * 4;
                #pragma unroll
                for (int rr = 0; rr < 4; ++rr) {
                    int gi = gi0 + rr;
                    atomicAdd(&C[(size_t)gi * NN + gj], acc[mt][nt2][rr]);
                }
            }
        }
    }
}

// ---------------- fallback (ws too small): fp32 LDS-tiled, correct-but-slow ----------------
__global__ void gemm_fallback(const float* __restrict__ A, const float* __restrict__ B,
                              float* __restrict__ C) {
    const int bi = blockIdx.y, bj = blockIdx.x;
    const int ty = threadIdx.y, tx = threadIdx.x;
    const int gi = bi * 32 + ty, gj = bj * 32 + tx;
    if (bi < bj) { C[(size_t)gi * NN + gj] = 0.f; return; }
    __shared__ float As[32][33], Bs[32][33];
    float s = 0.f;
    for (int kt = bj; kt <= bi; ++kt) {
        const int k = kt * 32;
        float av = A[(size_t)gi * NN + k + tx];
        As[ty][tx] = (k + tx <= gi) ? av : 0.f;
        float bv = B[(size_t)(k + ty) * NN + gj];
        Bs[ty][tx] = (k + ty >= gj) ? bv : 0.f;
        __syncthreads();
        #pragma unroll
        for (int kk = 0; kk < 32; ++kk) s += As[ty][kk] * Bs[kk][tx];
        __syncthreads();
    }
    C[(size_t)gi * NN + gj] = (gi >= gj) ? s : 0.f;
}

extern "C" void kernel_launch(void* const* d_in, const int* in_sizes, int n_in,
                              void* d_out, int out_size, void* d_ws, size_t ws_size,
                              hipStream_t stream) {
    const float* A = (const float*)d_in[0];
    const float* B = (const float*)d_in[1];
    float* C = (float*)d_out;

    const size_t need = (size_t)2 * NN * NN * sizeof(unsigned short);  // 64 MB
    if (ws_size >= need) {
        unsigned short* A2 = (unsigned short*)d_ws;
        unsigned short* B2 = A2 + (size_t)NN * NN;
        hipMemsetAsync(C, 0, (size_t)NN * NN * sizeof(float), stream);
        prep_all<<<dim3(2176), dim3(256), 0, stream>>>(A, B, A2, B2);
        gemm_tril<<<dim3(260), dim3(512), 0, stream>>>(A2, B2, C);
    } else {
        gemm_fallback<<<dim3(128, 128), dim3(32, 32), 0, stream>>>(A, B, C);
    }
}